// Round 1
// baseline (268.191 us; speedup 1.0000x reference)
//
#include <hip/hip_runtime.h>
#include <stdint.h>

#define NR 8192
#define DE 1024
#define DC 512
#define BIGF 9999999.0f
#define MARG 0.3f
#define NEGI -3.0e38f
#define POSI 3.0e38f

typedef __attribute__((ext_vector_type(8))) short bf16x8;
typedef __attribute__((ext_vector_type(4))) float f32x4;

typedef __attribute__((address_space(3))) unsigned int lds_u32;
typedef const __attribute__((address_space(1))) unsigned int glb_u32;

static __device__ __forceinline__ void ld_g2l16(const void* g, void* l) {
    __builtin_amdgcn_global_load_lds((glb_u32*)g, (lds_u32*)l, 16, 0, 0);
}

static __device__ __forceinline__ unsigned short f2bf(float x) {
    unsigned u = __float_as_uint(x);
    unsigned r = u + 0x7FFFu + ((u >> 16) & 1u);
    return (unsigned short)(r >> 16);
}

static __device__ __forceinline__ float b2f(short u) {
    return __uint_as_float(((unsigned)(unsigned short)u) << 16);
}

// ---------------- K1: emb -> bf16, sq[i] = ||emb_i||^2, class histogram ----------------
__global__ __launch_bounds__(256) void k_prep_emb(const float* __restrict__ emb,
                                                  const int* __restrict__ label,
                                                  short* __restrict__ embb,
                                                  float* __restrict__ sq,
                                                  int* __restrict__ cnt) {
    int row = blockIdx.x, tid = threadIdx.x;
    float4 v = ((const float4*)(emb + (size_t)row * DE))[tid];
    float s = v.x * v.x + v.y * v.y + v.z * v.z + v.w * v.w;
    ushort4 b;
    b.x = f2bf(v.x); b.y = f2bf(v.y); b.z = f2bf(v.z); b.w = f2bf(v.w);
    *(ushort4*)&embb[(size_t)row * DE + tid * 4] = b;
    for (int m = 1; m < 64; m <<= 1) s += __shfl_xor(s, m);
    __shared__ float red[4];
    if ((tid & 63) == 0) red[tid >> 6] = s;
    __syncthreads();
    if (tid == 0) {
        sq[row] = red[0] + red[1] + red[2] + red[3];
        atomicAdd(&cnt[label[row]], 1);
    }
}

// ---------------- K2: exclusive scan of class counts (512, single block) ----------------
__global__ __launch_bounds__(512) void k_scan(const int* __restrict__ cnt,
                                              int* __restrict__ clsOff) {
    __shared__ int s[512];
    int t = threadIdx.x;
    s[t] = cnt[t];
    __syncthreads();
    for (int d = 1; d < 512; d <<= 1) {
        int v = (t >= d) ? s[t - d] : 0;
        __syncthreads();
        s[t] += v;
        __syncthreads();
    }
    clsOff[t] = s[t] - cnt[t];
}

// ---------------- K3: scatter rows into class member lists ----------------
__global__ __launch_bounds__(256) void k_fill(const int* __restrict__ label,
                                              const int* __restrict__ clsOff,
                                              int* __restrict__ fill,
                                              int* __restrict__ list) {
    int i = blockIdx.x * 256 + threadIdx.x;
    int l = label[i];
    int p = atomicAdd(&fill[l], 1);
    list[clsOff[l] + p] = i;
}

// ---------------- K4: symmetric GEMM + min-of-negative row & column reductions ----------------
// Counted-vmcnt double-buffered pipeline (guide T3+T4+T5):
//  - tile 128x256, BK=32, 4 waves, per-wave 128x64 (acc[8][4]); 1056 upper-tri blocks,
//    2 blocks/CU resident (LDS 48KB, VGPR<=256 via launch_bounds(256,2)).
//  - per K-tile, 2 phases; each phase: {issue 3 global_load_lds for tile t+1 -> buf^1,
//    ds_read frags from buf, setprio(1), 16 MFMA, setprio(0), raw s_barrier}.
//  - vmcnt(3) once per tile (after phase-0 issues): retires tile-t's 6 loads while 3 of
//    t+1's stay in flight. Never drains to 0 in the main loop (only at kt==31).
//  - raw asm s_barrier (NOT __syncthreads) so the compiler does not emit vmcnt(0) drains.
//  - safety: stage(t+1) targets buf^1, last read by tile t-1; every wave passed the
//    end-of-(t-1) barrier before any wave can issue those loads. vmcnt+barrier at phase 0
//    guarantees all waves' tile-t loads landed before any ds_read of buf[t&1].
// Staging source swizzle + fragment pxor swizzle copied verbatim from the previous
// verified kernel (SQ_LDS_BANK_CONFLICT == 0 measured).
__global__ __launch_bounds__(256, 2) void k_main(const short* __restrict__ embb,
                                                 const float* __restrict__ sq,
                                                 const int* __restrict__ label,
                                                 unsigned* __restrict__ mnA) {
    // decode block -> (pr, pc): 128-row panel pr (0..63), 256-col panel pc >= pr>>1
    int L = blockIdx.x;
    int pr = 0, off = 0;
    while (off + (32 - (pr >> 1)) <= L) { off += 32 - (pr >> 1); ++pr; }
    const int pc = (pr >> 1) + (L - off);
    const int i0 = pr * 128, j0 = pc * 256;

    __shared__ __align__(16) short As[2][128 * 32];
    __shared__ __align__(16) short Bs[2][256 * 32];

    const int tid = threadIdx.x;
    const int lane = tid & 63;
    const int w = tid >> 6;
    const int q = lane >> 4, l15 = lane & 15;

    // staging source swizzle: slot rr = tid>>2, c = tid&3 -> global chunk g
    const int srow = tid >> 2;
    const int g = (tid & 3) ^ ((tid >> 3) & 3);
    const short* gA = embb + (size_t)(i0 + srow) * DE + g * 8;
    const short* gB = embb + (size_t)(j0 + srow) * DE + g * 8;

    // fragment read swizzle (conflict-free, measured 0 conflicts)
    const int pxor = q ^ ((l15 >> 1) & 3);

    f32x4 acc[8][4];
#pragma unroll
    for (int m = 0; m < 8; ++m)
#pragma unroll
        for (int n = 0; n < 4; ++n) acc[m][n] = (f32x4){0.f, 0.f, 0.f, 0.f};

    // one K-tile = A(128 rows): 2 calls + B(256 rows): 4 calls, 16B/thread/call
    auto stage_a = [&](int kt, int b) {
        const short* s = gA + kt * 32;
        ld_g2l16(s, &As[b][(size_t)tid * 8]);
        ld_g2l16(s + (size_t)64 * DE, &As[b][(size_t)(tid + 256) * 8]);
    };
    auto stage_b0 = [&](int kt, int b) {
        ld_g2l16(gB + kt * 32, &Bs[b][(size_t)tid * 8]);
    };
    auto stage_b123 = [&](int kt, int b) {
        const short* s = gB + kt * 32;
        ld_g2l16(s + (size_t)64 * DE, &Bs[b][(size_t)(tid + 256) * 8]);
        ld_g2l16(s + (size_t)128 * DE, &Bs[b][(size_t)(tid + 512) * 8]);
        ld_g2l16(s + (size_t)192 * DE, &Bs[b][(size_t)(tid + 768) * 8]);
    };

    // prologue: stage tile 0 into buf0 (6 loads in flight)
    stage_a(0, 0); stage_b0(0, 0); stage_b123(0, 0);

    int cur = 0;
    for (int kt = 0; kt < 32; ++kt) {
        // ---------------- phase 0: m=0..3 x n=0..3 ----------------
        if (kt < 31) {
            stage_a(kt + 1, cur ^ 1);
            stage_b0(kt + 1, cur ^ 1);
            asm volatile("s_waitcnt vmcnt(3)" ::: "memory");
        } else {
            asm volatile("s_waitcnt vmcnt(0)" ::: "memory");
        }
        asm volatile("s_barrier" ::: "memory");

        bf16x8 bfr[4], af[4];
#pragma unroll
        for (int n = 0; n < 4; ++n)
            bfr[n] = *(const bf16x8*)&Bs[cur][(w * 64 + n * 16 + l15) * 32 + pxor * 8];
#pragma unroll
        for (int m = 0; m < 4; ++m)
            af[m] = *(const bf16x8*)&As[cur][(m * 16 + l15) * 32 + pxor * 8];

        __builtin_amdgcn_s_setprio(1);
#pragma unroll
        for (int m = 0; m < 4; ++m)
#pragma unroll
            for (int n = 0; n < 4; ++n)
                acc[m][n] = __builtin_amdgcn_mfma_f32_16x16x32_bf16(af[m], bfr[n], acc[m][n], 0, 0, 0);
        __builtin_amdgcn_s_setprio(0);
        asm volatile("s_barrier" ::: "memory");

        // ---------------- phase 1: m=4..7 x n=0..3 ----------------
        if (kt < 31) stage_b123(kt + 1, cur ^ 1);
#pragma unroll
        for (int m = 0; m < 4; ++m)
            af[m] = *(const bf16x8*)&As[cur][((m + 4) * 16 + l15) * 32 + pxor * 8];

        __builtin_amdgcn_s_setprio(1);
#pragma unroll
        for (int m = 0; m < 4; ++m)
#pragma unroll
            for (int n = 0; n < 4; ++n)
                acc[m + 4][n] = __builtin_amdgcn_mfma_f32_16x16x32_bf16(af[m], bfr[n], acc[m + 4][n], 0, 0, 0);
        __builtin_amdgcn_s_setprio(0);
        asm volatile("s_barrier" ::: "memory");

        cur ^= 1;
    }

    // ---- epilogue: masked d2, row-min (registers+butterfly) & col-min -> atomicMin ----
    // diagonal-overlap tiles double-count pairs: harmless for min. self-pair masked by label.
    const int j0w = j0 + w * 64;
    float sqj[4]; int lbj[4];
#pragma unroll
    for (int n = 0; n < 4; ++n) {
        int cg = j0w + n * 16 + l15;
        sqj[n] = sq[cg]; lbj[n] = label[cg];
    }
    float cmn[4] = {POSI, POSI, POSI, POSI};
#pragma unroll
    for (int m = 0; m < 8; ++m) {
        float rm[4] = {POSI, POSI, POSI, POSI};
        float sqi[4]; int lbi[4];
#pragma unroll
        for (int rr = 0; rr < 4; ++rr) {
            int rg = i0 + m * 16 + q * 4 + rr;
            sqi[rr] = sq[rg]; lbi[rr] = label[rg];
        }
#pragma unroll
        for (int n = 0; n < 4; ++n)
#pragma unroll
            for (int rr = 0; rr < 4; ++rr) {
                float d2 = fmaf(-2.0f, acc[m][n][rr], sqi[rr] + sqj[n]);
                d2 = fmaxf(d2, 1e-12f);
                float dn = (lbi[rr] == lbj[n]) ? POSI : d2;
                rm[rr] = fminf(rm[rr], dn);
                cmn[n] = fminf(cmn[n], dn);
            }
#pragma unroll
        for (int rr = 0; rr < 4; ++rr) {
            float v = rm[rr];
            v = fminf(v, __shfl_xor(v, 1));
            v = fminf(v, __shfl_xor(v, 2));
            v = fminf(v, __shfl_xor(v, 4));
            v = fminf(v, __shfl_xor(v, 8));
            if (l15 == 0) atomicMin(&mnA[i0 + m * 16 + q * 4 + rr], __float_as_uint(v));
        }
    }
#pragma unroll
    for (int n = 0; n < 4; ++n) {
        float v = cmn[n];
        v = fminf(v, __shfl_xor(v, 16));
        v = fminf(v, __shfl_xor(v, 32));
        if (q == 0) atomicMin(&mnA[j0w + n * 16 + l15], __float_as_uint(v));
    }
}

// ---------------- K5: exact per-row positives (top-2 over classmates) + alphas ----------------
__global__ __launch_bounds__(256) void k_pos(const short* __restrict__ embb,
                                             const float* __restrict__ sq,
                                             const float* __restrict__ clot,
                                             const int* __restrict__ label,
                                             const int* __restrict__ cnt,
                                             const int* __restrict__ clsOff,
                                             const int* __restrict__ clsList,
                                             const unsigned* __restrict__ mnA,
                                             float* __restrict__ ap1, float* __restrict__ ap2,
                                             float* __restrict__ an,
                                             float* __restrict__ alpha1, float* __restrict__ alpha2) {
    int wid = threadIdx.x >> 6, lane = threadIdx.x & 63;
    int row = blockIdx.x * 4 + wid;
    int lb = label[row];
    int cc = cnt[lb], off = clsOff[lb];
    float sqiv = sq[row];

    const bf16x8* rp = (const bf16x8*)(embb + (size_t)row * DE + lane * 16);
    bf16x8 ra = rp[0], rb = rp[1];
    float rf[16];
#pragma unroll
    for (int t = 0; t < 8; ++t) { rf[t] = b2f(ra[t]); rf[8 + t] = b2f(rb[t]); }

    float v1 = NEGI, v2 = NEGI;
    int i1 = 0, i2 = 0;
    for (int m = 0; m < cc; ++m) {
        int j = clsList[off + m];
        float d2;
        if (j == row) {
            d2 = 1e-12f;
        } else {
            const bf16x8* jp = (const bf16x8*)(embb + (size_t)j * DE + lane * 16);
            bf16x8 ja = jp[0], jb = jp[1];
            float s = 0.f;
#pragma unroll
            for (int t = 0; t < 8; ++t) s = fmaf(rf[t], b2f(ja[t]), s);
#pragma unroll
            for (int t = 0; t < 8; ++t) s = fmaf(rf[8 + t], b2f(jb[t]), s);
            for (int mm = 1; mm < 64; mm <<= 1) s += __shfl_xor(s, mm);
            d2 = fmaxf(fmaf(-2.0f, s, sqiv + sq[j]), 1e-12f);
        }
        bool t1 = (d2 > v1) || (d2 == v1 && j < i1);
        bool t2 = (d2 > v2) || (d2 == v2 && j < i2);
        v2 = t1 ? v1 : (t2 ? d2 : v2);
        i2 = t1 ? i1 : (t2 ? j : i2);
        v1 = t1 ? d2 : v1;
        i1 = t1 ? j : i1;
    }

    float a1 = sqrtf(v1);
    int j1 = i1;
    float a2v; int j2;
    if (cc >= 2) {
        a2v = sqrtf(v2);
        j2 = i2;
    } else {
        // singleton class: ref falls back to best (max-dist) negative - BIG
        float kv = NEGI; int ki = 0;
        for (int c = lane; c < NR; c += 64) {
            if (label[c] == lb) continue;
            float s = 0.f;
            const short* crow = embb + (size_t)c * DE;
            const short* rrow = embb + (size_t)row * DE;
            for (int t = 0; t < DE; ++t) s = fmaf(b2f(rrow[t]), b2f(crow[t]), s);
            float d2c = fmaxf(fmaf(-2.0f, s, sqiv + sq[c]), 1e-12f);
            bool tk = (d2c > kv) || (d2c == kv && c < ki);
            kv = tk ? d2c : kv; ki = tk ? c : ki;
        }
        for (int mm = 1; mm < 64; mm <<= 1) {
            float ov = __shfl_xor(kv, mm); int oi = __shfl_xor(ki, mm);
            bool tk = (ov > kv) || (ov == kv && oi < ki);
            kv = tk ? ov : kv; ki = tk ? oi : ki;
        }
        a2v = sqrtf(kv) - BIGF;
        j2 = ki;
    }

    // alpha dots + norms over clot
    const float4* c4 = (const float4*)clot;
    float s1 = 0.f, s2 = 0.f, n0 = 0.f, n1 = 0.f, n2 = 0.f;
    for (int t = lane; t < DC / 4; t += 64) {
        float4 a = c4[(size_t)row * (DC / 4) + t];
        float4 b1 = c4[(size_t)j1 * (DC / 4) + t];
        float4 b2 = c4[(size_t)j2 * (DC / 4) + t];
        s1 += a.x * b1.x + a.y * b1.y + a.z * b1.z + a.w * b1.w;
        s2 += a.x * b2.x + a.y * b2.y + a.z * b2.z + a.w * b2.w;
        n0 += a.x * a.x + a.y * a.y + a.z * a.z + a.w * a.w;
        n1 += b1.x * b1.x + b1.y * b1.y + b1.z * b1.z + b1.w * b1.w;
        n2 += b2.x * b2.x + b2.y * b2.y + b2.z * b2.z + b2.w * b2.w;
    }
    for (int mm = 1; mm < 64; mm <<= 1) {
        s1 += __shfl_xor(s1, mm); s2 += __shfl_xor(s2, mm);
        n0 += __shfl_xor(n0, mm); n1 += __shfl_xor(n1, mm); n2 += __shfl_xor(n2, mm);
    }
    if (lane == 0) {
        ap1[row] = a1; ap2[row] = a2v;
        an[row] = sqrtf(__uint_as_float(mnA[row]));
        alpha1[row] = s1 / (sqrtf(n0) * sqrtf(n1));
        alpha2[row] = s2 / (sqrtf(n0) * sqrtf(n2));
    }
}

// ---------------- K7: final loss + prec ----------------
__global__ __launch_bounds__(256) void k_final(const float* __restrict__ ap1, const float* __restrict__ ap2,
                                               const float* __restrict__ an,
                                               const float* __restrict__ alpha1, const float* __restrict__ alpha2,
                                               float* __restrict__ out) {
    int tid = threadIdx.x;
    float sl11 = 0.f, sl13 = 0.f, sp = 0.f;
    for (int row = tid; row < NR; row += 256) {
        float a1 = alpha1[row], a2 = alpha2[row];
        float dap1 = ap1[row], dap2 = ap2[row], dan = an[row];
        float y = (a1 < a2) ? -1.f : 1.f;
        float ym = (a1 == a2) ? 0.f : 1.f;
        float x1 = dap2 * ym;
        float x2 = dap1 * ym + MARG * (a1 - a2 - y);
        sl11 += fmaxf(0.f, -y * (x1 - x2) + MARG);
        float ap1m = dap1 + MARG * (a1 - 1.f);
        sl13 += fmaxf(0.f, -(dan - ap1m) + MARG);
        sp += (dan > ap1m) ? 1.f : 0.f;
    }
    for (int m = 1; m < 64; m <<= 1) {
        sl11 += __shfl_xor(sl11, m);
        sl13 += __shfl_xor(sl13, m);
        sp += __shfl_xor(sp, m);
    }
    __shared__ float r11[4], r13[4], rp[4];
    if ((tid & 63) == 0) { r11[tid >> 6] = sl11; r13[tid >> 6] = sl13; rp[tid >> 6] = sp; }
    __syncthreads();
    if (tid == 0) {
        float t11 = r11[0] + r11[1] + r11[2] + r11[3];
        float t13 = r13[0] + r13[1] + r13[2] + r13[3];
        float tp = rp[0] + rp[1] + rp[2] + rp[3];
        out[0] = 0.1f * (t11 / (float)NR) + t13 / (float)NR;
        out[1] = tp / (float)NR;
    }
}

extern "C" void kernel_launch(void* const* d_in, const int* in_sizes, int n_in,
                              void* d_out, int out_size, void* d_ws, size_t ws_size,
                              hipStream_t stream) {
    const float* emb = (const float*)d_in[0];
    const int* label = (const int*)d_in[1];
    const float* clot = (const float*)d_in[2];
    float* out = (float*)d_out;

    char* ws = (char*)d_ws;
    size_t off = 0;
    auto alloc = [&](size_t bytes) -> char* {
        char* p = ws + off;
        off = (off + bytes + 255) & ~(size_t)255;
        return p;
    };
    short*    embb = (short*)alloc((size_t)NR * DE * 2);
    float*    sq   = (float*)alloc(NR * 4);
    int*      cnt  = (int*)alloc(512 * 4);
    int*      cOff = (int*)alloc(512 * 4);
    int*      fill = (int*)alloc(512 * 4);
    int*      list = (int*)alloc(NR * 4);
    unsigned* mnA  = (unsigned*)alloc((size_t)NR * 4);
    float*    ap1  = (float*)alloc(NR * 4);
    float*    ap2  = (float*)alloc(NR * 4);
    float*    an   = (float*)alloc(NR * 4);
    float*    al1  = (float*)alloc(NR * 4);
    float*    al2  = (float*)alloc(NR * 4);

    hipMemsetAsync(cnt, 0, 512 * 4, stream);
    hipMemsetAsync(fill, 0, 512 * 4, stream);
    hipMemsetAsync(mnA, 0xFF, (size_t)NR * 4, stream);   // large bits: +inf for positive-float min

    k_prep_emb<<<dim3(NR), dim3(256), 0, stream>>>(emb, label, embb, sq, cnt);
    k_scan<<<dim3(1), dim3(512), 0, stream>>>(cnt, cOff);
    k_fill<<<dim3(NR / 256), dim3(256), 0, stream>>>(label, cOff, fill, list);
    k_main<<<dim3(1056), dim3(256), 0, stream>>>(embb, sq, label, mnA);
    k_pos<<<dim3(NR / 4), dim3(256), 0, stream>>>(embb, sq, clot, label, cnt, cOff, list,
                                                  mnA, ap1, ap2, an, al1, al2);
    k_final<<<dim3(1), dim3(256), 0, stream>>>(ap1, ap2, an, al1, al2, out);
}